// Round 1
// baseline (590.504 us; speedup 1.0000x reference)
//
#include <hip/hip_runtime.h>

// EEG train-time augmentation, fully fused elementwise pass.
// x: [B,T,N] f32, chdrop_u: [B,1,N] f32, noise: [B,T,N] f32,
// tm_u: [B] f32, t0: [B] i32  ->  out: [B,T,N] f32
//
// out = tmask ? 0 : (chdrop_u[b,n] < 0.1 ? 0 : x) + 0.02*noise
// tmask = (tm_u[b] < 0.1) && (t0[b] <= t < t0[b]+32)
//
// B=256, T=2048, N=128 (powers of two -> shift/mask index math).
// Memory-bound: 768 MB total traffic -> ~122 us floor at 6.3 TB/s.

__global__ __launch_bounds__(256) void eeg_aug_kernel(
    const float4* __restrict__ x,
    const float4* __restrict__ chdrop,   // [B, N/4]
    const float4* __restrict__ noise,
    const float*  __restrict__ tm_u,     // [B]
    const int*    __restrict__ t0,       // [B]
    float4* __restrict__ out,
    int total4)                          // B*T*N/4
{
    constexpr float P_CHDROP  = 0.1f;
    constexpr float NOISE_STD = 0.02f;
    constexpr float P_TMASK   = 0.1f;
    constexpr int   MLEN      = 32;
    // Per-sample geometry (fixed by reference): N/4 = 32 float4 per row,
    // T = 2048 rows, T*N/4 = 65536 float4 per sample.
    const int stride = gridDim.x * blockDim.x;
    for (int i = blockIdx.x * blockDim.x + threadIdx.x; i < total4; i += stride) {
        const int n4 = i & 31;           // float4 index within channel dim
        const int t  = (i >> 5) & 2047;  // time index
        const int b  = i >> 16;          // sample index

        const float4 xv = x[i];
        const float4 nv = noise[i];
        const float4 cd = chdrop[(b << 5) + n4];   // L2-resident (128 KB)
        const float  tmu = tm_u[b];
        const int    s0  = t0[b];

        // channel dropout (branchless select) + noise
        float4 o;
        o.x = (cd.x < P_CHDROP ? 0.0f : xv.x) + NOISE_STD * nv.x;
        o.y = (cd.y < P_CHDROP ? 0.0f : xv.y) + NOISE_STD * nv.y;
        o.z = (cd.z < P_CHDROP ? 0.0f : xv.z) + NOISE_STD * nv.z;
        o.w = (cd.w < P_CHDROP ? 0.0f : xv.w) + NOISE_STD * nv.w;

        // temporal mask: zero the whole row (noise included)
        const bool masked = (tmu < P_TMASK) & (t >= s0) & (t < s0 + MLEN);
        if (masked) { o.x = 0.0f; o.y = 0.0f; o.z = 0.0f; o.w = 0.0f; }

        out[i] = o;
    }
}

extern "C" void kernel_launch(void* const* d_in, const int* in_sizes, int n_in,
                              void* d_out, int out_size, void* d_ws, size_t ws_size,
                              hipStream_t stream) {
    const float4* x      = (const float4*)d_in[0];
    const float4* chdrop = (const float4*)d_in[1];
    const float4* noise  = (const float4*)d_in[2];
    const float*  tm_u   = (const float*)d_in[3];
    const int*    t0     = (const int*)d_in[4];
    float4* out = (float4*)d_out;

    const int total4 = in_sizes[0] / 4;          // 16,777,216
    const int block = 256;
    int grid = (total4 + block - 1) / block;
    if (grid > 2048) grid = 2048;                // grid-stride; ~8 blocks/CU

    eeg_aug_kernel<<<grid, block, 0, stream>>>(x, chdrop, noise, tm_u, t0, out, total4);
}